// Round 1
// baseline (695.472 us; speedup 1.0000x reference)
//
#include <hip/hip_runtime.h>

typedef __attribute__((ext_vector_type(8))) __bf16 bf16x8;
typedef __attribute__((ext_vector_type(16))) float f32x16;

__device__ __forceinline__ unsigned short f2bf(float f) {
    unsigned int u = __float_as_uint(f);
    unsigned int r = (u + 0x7FFFu + ((u >> 16) & 1u)) >> 16;
    return (unsigned short)r;
}

// ---------------------------------------------------------------------------
// Kernel A: conv1 (41x11, stride (2,2), pad (20,5)) + bias + bn1 + clip(0,20)
//           + time-mask.  x[16,1,161,1024] f32 -> h1[16,32,81,512] bf16 (ws)
// block (64,4): tx = ow lane, ty>>1 = oh sub (2 rows/block), ty&1 = oc octet.
// grid (8 ow-tiles, 41 oh-pairs, 16n * 2 oc-groups)
// ---------------------------------------------------------------------------
__global__ __launch_bounds__(256) void conv1_fused(
    const float* __restrict__ x, const int* __restrict__ xlen,
    const float* __restrict__ w1, const float* __restrict__ b1,
    const float* __restrict__ g1, const float* __restrict__ be1,
    const float* __restrict__ m1, const float* __restrict__ v1,
    unsigned short* __restrict__ h1)
{
    __shared__ float xs[43 * 138];      // rows 4*by-20 .. +42, cols 128*bx-5 .. +132 (138 = even pad)
    __shared__ float ws16[41 * 11 * 16];// [kh][kw][16 oc of this group]

    const int tx = threadIdx.x;
    const int ty = threadIdx.y;
    const int t  = ty * 64 + tx;
    const int bx = blockIdx.x;
    const int by = blockIdx.y;
    const int n   = blockIdx.z >> 1;
    const int ocg = blockIdx.z & 1;

    for (int idx = t; idx < 43 * 138; idx += 256) {
        const int r = idx / 138;
        const int c = idx - r * 138;
        const int gr = 4 * by - 20 + r;
        const int gc = 128 * bx - 5 + c;
        float v = 0.f;
        if (gr >= 0 && gr < 161 && gc >= 0 && gc < 1024)
            v = x[(n * 161 + gr) * 1024 + gc];
        xs[idx] = v;
    }
    for (int idx = t; idx < 41 * 11 * 16; idx += 256) {
        const int j  = idx & 15;
        const int tt = idx >> 4;
        const int kw = tt % 11;
        const int kh = tt / 11;
        ws16[idx] = w1[((ocg * 16 + j) * 41 + kh) * 11 + kw];
    }
    __syncthreads();

    const int os = ty >> 1;        // which of the 2 oh rows
    const int w8 = (ty & 1) * 8;   // oc octet base within the 16

    float acc[8];
    #pragma unroll
    for (int j = 0; j < 8; ++j) acc[j] = 0.f;

    for (int kh = 0; kh < 41; ++kh) {
        const float* rowp = &xs[(2 * os + kh) * 138 + 2 * tx];
        float xv[12];
        #pragma unroll
        for (int q = 0; q < 6; ++q) {
            const float2 t2 = *(const float2*)(rowp + 2 * q);  // 8B aligned (even cols)
            xv[2 * q] = t2.x; xv[2 * q + 1] = t2.y;
        }
        #pragma unroll
        for (int kw = 0; kw < 11; ++kw) {
            const float4 wa = *(const float4*)&ws16[(kh * 11 + kw) * 16 + w8];
            const float4 wb = *(const float4*)&ws16[(kh * 11 + kw) * 16 + w8 + 4];
            const float xvv = xv[kw];
            acc[0] = fmaf(xvv, wa.x, acc[0]);
            acc[1] = fmaf(xvv, wa.y, acc[1]);
            acc[2] = fmaf(xvv, wa.z, acc[2]);
            acc[3] = fmaf(xvv, wa.w, acc[3]);
            acc[4] = fmaf(xvv, wb.x, acc[4]);
            acc[5] = fmaf(xvv, wb.y, acc[5]);
            acc[6] = fmaf(xvv, wb.z, acc[6]);
            acc[7] = fmaf(xvv, wb.w, acc[7]);
        }
    }

    const int oh = by * 2 + os;
    if (oh >= 81) return;
    const int ow  = bx * 64 + tx;
    const int len = xlen[n];
    #pragma unroll
    for (int j = 0; j < 8; ++j) {
        const int c = ocg * 16 + w8 + j;
        const float s = g1[c] * rsqrtf(v1[c] + 1e-5f);
        float val = (acc[j] + b1[c] - m1[c]) * s + be1[c];
        val = fminf(fmaxf(val, 0.f), 20.f);
        if (ow >= len) val = 0.f;
        h1[((n * 32 + c) * 81 + oh) * 512 + ow] = f2bf(val);
    }
}

// ---------------------------------------------------------------------------
// Kernel B: w2 [32oc][32ic][21][11] f32 -> w2T [tap=kh*11+kw][oc][ic] bf16
// 236544 elements; t decomposes directly into the destination index.
// ---------------------------------------------------------------------------
__global__ __launch_bounds__(256) void prep_w2(const float* __restrict__ w2,
                                               unsigned short* __restrict__ w2t)
{
    const int t = blockIdx.x * 256 + threadIdx.x;   // grid sized exactly
    const int ic  = t & 31;
    const int oc  = (t >> 5) & 31;
    const int tap = t >> 10;                        // 0..230
    const int kh  = tap / 11;
    const int kw  = tap - kh * 11;
    w2t[t] = f2bf(w2[((oc * 32 + ic) * 21 + kh) * 11 + kw]);
}

// ---------------------------------------------------------------------------
// Kernel C: conv2 (32ic, 21x11, stride (2,1), pad (10,5)) + bias + bn2 +
//           clip(0,20) + time-mask, via v_mfma_f32_32x32x16_bf16.
// Per tap: rank-32 update C[oc][ow] += W[oc][ic] * H[ic][col].
// block = 256 thr = 4 waves; wave w owns cols [w*64, w*64+64) of a 256-col
// tile (2 C-frags of 32x32, M = all 32 oc). grid (2 col-tiles, 41 oh2, 16 n).
// LDS: lb[col 0..265][ic padded to 40] bf16, staged per kh (row r of h1).
// ---------------------------------------------------------------------------
__global__ __launch_bounds__(256) void conv2_fused(
    const unsigned short* __restrict__ h1, const unsigned short* __restrict__ w2t,
    const int* __restrict__ xlen,
    const float* __restrict__ b2, const float* __restrict__ g2,
    const float* __restrict__ be2, const float* __restrict__ m2,
    const float* __restrict__ v2, float* __restrict__ out)
{
    __shared__ unsigned short lb[266 * 40];

    const int tid = threadIdx.x;
    const int w   = tid >> 6;     // wave 0..3
    const int l   = tid & 63;     // lane
    const int l31 = l & 31;
    const int lhi = l >> 5;       // 0/1
    const int oh2 = blockIdx.y;
    const int n   = blockIdx.z;
    const int ow0 = blockIdx.x * 256;

    f32x16 acc0 = {};
    f32x16 acc1 = {};

    const int p   = tid >> 4;     // ic pair 0..15 (staging role)
    const int l16 = tid & 15;

    for (int kh = 0; kh < 21; ++kh) {
        const int r = 2 * oh2 + kh - 10;
        if (r < 0 || r >= 81) continue;   // uniform across block
        __syncthreads();                  // protect prev-iter readers
        const unsigned short* hrow = h1 + ((n * 32 + 2 * p) * 81 + r) * 512;
        #pragma unroll
        for (int s = 0; s < 17; ++s) {
            const int col = l16 + (s << 4);
            if (col < 266) {
                const int gc = ow0 + col - 5;
                unsigned int v = 0;
                if (gc >= 0 && gc < 512)
                    v = (unsigned int)hrow[gc] |
                        ((unsigned int)hrow[gc + 81 * 512] << 16);  // ic 2p, 2p+1
                *(unsigned int*)&lb[col * 40 + 2 * p] = v;
            }
        }
        __syncthreads();

        #pragma unroll
        for (int kw = 0; kw < 11; ++kw) {
            const int tap = kh * 11 + kw;
            // A[m=oc][k=ic]: lane -> m = l&31, k = (l>>5)*8 + j  (2 K-halves)
            const unsigned short* ap = w2t + tap * 1024 + l31 * 32 + lhi * 8;
            const bf16x8 a0 = *(const bf16x8*)(ap);
            const bf16x8 a1 = *(const bf16x8*)(ap + 16);
            // B[k=ic][nn=col]: lane -> nn = l&31, k = (l>>5)*8 + j
            const unsigned short* bp = &lb[((w << 6) + l31 + kw) * 40 + lhi * 8];
            const bf16x8 b00 = *(const bf16x8*)(bp);
            const bf16x8 b01 = *(const bf16x8*)(bp + 16);
            const bf16x8 b10 = *(const bf16x8*)(bp + 32 * 40);
            const bf16x8 b11 = *(const bf16x8*)(bp + 32 * 40 + 16);
            acc0 = __builtin_amdgcn_mfma_f32_32x32x16_bf16(a0, b00, acc0, 0, 0, 0);
            acc0 = __builtin_amdgcn_mfma_f32_32x32x16_bf16(a1, b01, acc0, 0, 0, 0);
            acc1 = __builtin_amdgcn_mfma_f32_32x32x16_bf16(a0, b10, acc1, 0, 0, 0);
            acc1 = __builtin_amdgcn_mfma_f32_32x32x16_bf16(a1, b11, acc1, 0, 0, 0);
        }
    }

    const int len = xlen[n];
    #pragma unroll
    for (int g = 0; g < 2; ++g) {
        const int ow = ow0 + (w << 6) + (g << 5) + l31;
        const bool valid = ow < len;
        #pragma unroll
        for (int reg = 0; reg < 16; ++reg) {
            // C/D layout (m74/m101): col = lane&31, row = (reg&3)+8*(reg>>2)+4*(lane>>5)
            const int oc = (reg & 3) + ((reg >> 2) << 3) + (lhi << 2);
            const float s = g2[oc] * rsqrtf(v2[oc] + 1e-5f);
            float val = ((g ? acc1[reg] : acc0[reg]) + b2[oc] - m2[oc]) * s + be2[oc];
            val = fminf(fmaxf(val, 0.f), 20.f);
            if (!valid) val = 0.f;
            out[((size_t)(n * 32 + oc) * 41 + oh2) * 512 + ow] = val;
        }
    }
}

extern "C" void kernel_launch(void* const* d_in, const int* in_sizes, int n_in,
                              void* d_out, int out_size, void* d_ws, size_t ws_size,
                              hipStream_t stream) {
    const float* x    = (const float*)d_in[0];
    const int*   xlen = (const int*)  d_in[1];
    const float* w1   = (const float*)d_in[2];
    const float* b1   = (const float*)d_in[3];
    const float* g1   = (const float*)d_in[4];
    const float* be1  = (const float*)d_in[5];
    const float* m1   = (const float*)d_in[6];
    const float* v1   = (const float*)d_in[7];
    const float* w2   = (const float*)d_in[8];
    const float* b2   = (const float*)d_in[9];
    const float* g2   = (const float*)d_in[10];
    const float* be2  = (const float*)d_in[11];
    const float* m2   = (const float*)d_in[12];
    const float* v2   = (const float*)d_in[13];
    float* out = (float*)d_out;

    // workspace layout: h1 bf16 [16*32*81*512] = 42,467,328 B, then w2T bf16
    unsigned short* h1  = (unsigned short*)d_ws;
    unsigned short* w2t = h1 + 21233664;

    conv1_fused<<<dim3(8, 41, 32), dim3(64, 4), 0, stream>>>(
        x, xlen, w1, b1, g1, be1, m1, v1, h1);
    prep_w2<<<dim3(924), dim3(256), 0, stream>>>(w2, w2t);
    conv2_fused<<<dim3(2, 41, 16), dim3(256), 0, stream>>>(
        h1, w2t, xlen, b2, g2, be2, m2, v2, out);
}

// Round 2
// 387.818 us; speedup vs baseline: 1.7933x; 1.7933x over previous
//
#include <hip/hip_runtime.h>

typedef __attribute__((ext_vector_type(8))) __bf16 bf16x8;
typedef __attribute__((ext_vector_type(16))) float f32x16;

__device__ __forceinline__ unsigned short f2bf(float f) {
    unsigned int u = __float_as_uint(f);
    unsigned int r = (u + 0x7FFFu + ((u >> 16) & 1u)) >> 16;
    return (unsigned short)r;
}

// ---------------------------------------------------------------------------
// prep_w1t: w1 [32oc][1][41kh][11kw] f32 -> w1t [kw][oc][kh pad 48] bf16.
// kh 41..47 zeroed (A-side zero-padding annihilates garbage B rows).
// ---------------------------------------------------------------------------
__global__ __launch_bounds__(256) void prep_w1t(const float* __restrict__ w1,
                                                unsigned short* __restrict__ w1t)
{
    const int t = blockIdx.x * 256 + threadIdx.x;   // grid 66 -> exactly 16896
    const int k    = t % 48;
    const int rest = t / 48;
    const int oc   = rest & 31;
    const int kw   = rest >> 5;
    unsigned short v = 0;
    if (k < 41) v = f2bf(w1[(oc * 41 + k) * 11 + kw]);
    w1t[t] = v;
}

// ---------------------------------------------------------------------------
// prep_w2: w2 [32oc][32ic][21][11] f32 -> w2T [tap=kh*11+kw][oc][ic] bf16
// ---------------------------------------------------------------------------
__global__ __launch_bounds__(256) void prep_w2(const float* __restrict__ w2,
                                               unsigned short* __restrict__ w2t)
{
    const int t = blockIdx.x * 256 + threadIdx.x;   // grid 924 -> exactly 236544
    const int ic  = t & 31;
    const int oc  = (t >> 5) & 31;
    const int tap = t >> 10;                        // 0..230
    const int kh  = tap / 11;
    const int kw  = tap - kh * 11;
    w2t[t] = f2bf(w2[((oc * 32 + ic) * 21 + kh) * 11 + kw]);
}

// ---------------------------------------------------------------------------
// conv1_mfma: conv1 (41x11, s(2,2), p(20,5)) + bias + bn1 + clip + mask
//   as 11 kw-taps of an M=32(oc) x K=48(kh,zero-pad) x N=ow GEMM on
//   v_mfma_f32_32x32x16_bf16.
// Block 256 thr = 4 waves; tile = 128 ow x 2 oh rows {oh0, oh0+4}
// (delta=4 keeps every kh-window 16B-chunk-aligned for ds_read_b128).
// LDS: xT[col 0..265][row 0..63] bf16, 128B/col pitch, chunk-XOR swizzle
//   byte = col*128 + ((chunk ^ ((col>>1)&7))<<4)  -> conflict-free reads.
// Rows staged: 0..55 (r = 2*oh0-20+row, zero-filled OOB); chunks read <= 6.
// grid (4 ow-tiles, 41 oh-groups, 16 n).
// ---------------------------------------------------------------------------
__global__ __launch_bounds__(256) void conv1_mfma(
    const float* __restrict__ x, const int* __restrict__ xlen,
    const unsigned short* __restrict__ w1t,
    const float* __restrict__ b1, const float* __restrict__ g1,
    const float* __restrict__ be1, const float* __restrict__ m1,
    const float* __restrict__ v1,
    unsigned short* __restrict__ h1)
{
    __shared__ uint4 lds4[2128];            // 266 cols * 128 B = 34048 B
    char* lds = (char*)lds4;

    const int t  = threadIdx.x;
    const int bx = blockIdx.x;
    const int yi = blockIdx.y;
    const int n  = blockIdx.z;
    const int oh0 = ((yi >> 2) << 3) + (yi & 3);   // yi 0..39 -> {8a+b}; yi40 -> 80

    // ---- stage: x f32 -> bf16, transposed, swizzled ----
    const int cw   = t & 63;
    const int jrow = t >> 6;
    const int gr0  = 2 * oh0 - 20;
    const int gc0  = bx * 256 - 5;
    const float* xn = x + (size_t)n * 161 * 1024;
    #pragma unroll
    for (int cg = 0; cg < 5; ++cg) {
        const int c = cg * 64 + cw;
        if (c < 266) {
            const int gc = gc0 + c;
            const bool cok = (gc >= 0) && (gc < 1024);
            #pragma unroll
            for (int jj = 0; jj < 2; ++jj) {
                const int j = jrow + 4 * jj;       // chunk 0..6
                if (j < 7) {
                    unsigned int u[4];
                    #pragma unroll
                    for (int q = 0; q < 4; ++q) {
                        const int rA = gr0 + 8 * j + 2 * q;
                        float lo = 0.f, hi = 0.f;
                        if (cok && rA >= 0 && rA < 161)      lo = xn[(size_t)rA * 1024 + gc];
                        if (cok && rA + 1 >= 0 && rA + 1 < 161) hi = xn[(size_t)(rA + 1) * 1024 + gc];
                        u[q] = (unsigned int)f2bf(lo) | ((unsigned int)f2bf(hi) << 16);
                    }
                    uint4 val; val.x = u[0]; val.y = u[1]; val.z = u[2]; val.w = u[3];
                    *(uint4*)(lds + c * 128 + ((j ^ ((c >> 1) & 7)) << 4)) = val;
                }
            }
        }
    }
    __syncthreads();

    // ---- compute ----
    const int l   = t & 63;
    const int w   = t >> 6;
    const int l31 = l & 31;
    const int lhi = l >> 5;
    const int i   = (w << 5) + l31;        // 0..127: ow within tile

    f32x16 acc0 = {}, acc1 = {};
    const char* w1tb = (const char*)w1t;
    #pragma unroll
    for (int kw = 0; kw < 11; ++kw) {
        const char* ap = w1tb + kw * 3072 + l31 * 96 + lhi * 16;
        const bf16x8 a0 = *(const bf16x8*)(ap);
        const bf16x8 a1 = *(const bf16x8*)(ap + 32);
        const bf16x8 a2 = *(const bf16x8*)(ap + 64);
        const int c = 2 * i + kw;          // local x col, <= 264
        const char* cb = lds + c * 128;
        const int sw = (c >> 1) & 7;
        // chunk = (delta>>2) + 2*s + lhi
        const bf16x8 b00 = *(const bf16x8*)(cb + (((0 + lhi) ^ sw) << 4));
        const bf16x8 b01 = *(const bf16x8*)(cb + (((2 + lhi) ^ sw) << 4));
        const bf16x8 b02 = *(const bf16x8*)(cb + (((4 + lhi) ^ sw) << 4));
        const bf16x8 b10 = *(const bf16x8*)(cb + (((1 + lhi) ^ sw) << 4));
        const bf16x8 b11 = *(const bf16x8*)(cb + (((3 + lhi) ^ sw) << 4));
        const bf16x8 b12 = *(const bf16x8*)(cb + (((5 + lhi) ^ sw) << 4));
        acc0 = __builtin_amdgcn_mfma_f32_32x32x16_bf16(a0, b00, acc0, 0, 0, 0);
        acc0 = __builtin_amdgcn_mfma_f32_32x32x16_bf16(a1, b01, acc0, 0, 0, 0);
        acc0 = __builtin_amdgcn_mfma_f32_32x32x16_bf16(a2, b02, acc0, 0, 0, 0);
        acc1 = __builtin_amdgcn_mfma_f32_32x32x16_bf16(a0, b10, acc1, 0, 0, 0);
        acc1 = __builtin_amdgcn_mfma_f32_32x32x16_bf16(a1, b11, acc1, 0, 0, 0);
        acc1 = __builtin_amdgcn_mfma_f32_32x32x16_bf16(a2, b12, acc1, 0, 0, 0);
    }

    // ---- epilogue: bias + bn1 + clip + time-mask -> h1 bf16 ----
    const int len = xlen[n];
    const int ow  = bx * 128 + i;
    const bool vmask = ow < len;
    #pragma unroll
    for (int d1 = 0; d1 < 2; ++d1) {
        const int oh = oh0 + 4 * d1;
        if (oh <= 80) {
            #pragma unroll
            for (int reg = 0; reg < 16; ++reg) {
                const int oc = (reg & 3) + ((reg >> 2) << 3) + (lhi << 2);
                const float s = g1[oc] * rsqrtf(v1[oc] + 1e-5f);
                float val = ((d1 ? acc1[reg] : acc0[reg]) + b1[oc] - m1[oc]) * s + be1[oc];
                val = fminf(fmaxf(val, 0.f), 20.f);
                if (!vmask) val = 0.f;
                h1[((size_t)(n * 32 + oc) * 81 + oh) * 512 + ow] = f2bf(val);
            }
        }
    }
}

// ---------------------------------------------------------------------------
// conv2_fused: unchanged from round 1 (passing). 32ic, 21x11, s(2,1), p(10,5),
// bias + bn2 + clip + mask via v_mfma_f32_32x32x16_bf16.
// ---------------------------------------------------------------------------
__global__ __launch_bounds__(256) void conv2_fused(
    const unsigned short* __restrict__ h1, const unsigned short* __restrict__ w2t,
    const int* __restrict__ xlen,
    const float* __restrict__ b2, const float* __restrict__ g2,
    const float* __restrict__ be2, const float* __restrict__ m2,
    const float* __restrict__ v2, float* __restrict__ out)
{
    __shared__ unsigned short lb[266 * 40];

    const int tid = threadIdx.x;
    const int w   = tid >> 6;
    const int l   = tid & 63;
    const int l31 = l & 31;
    const int lhi = l >> 5;
    const int oh2 = blockIdx.y;
    const int n   = blockIdx.z;
    const int ow0 = blockIdx.x * 256;

    f32x16 acc0 = {};
    f32x16 acc1 = {};

    const int p   = tid >> 4;
    const int l16 = tid & 15;

    for (int kh = 0; kh < 21; ++kh) {
        const int r = 2 * oh2 + kh - 10;
        if (r < 0 || r >= 81) continue;
        __syncthreads();
        const unsigned short* hrow = h1 + ((n * 32 + 2 * p) * 81 + r) * 512;
        #pragma unroll
        for (int s = 0; s < 17; ++s) {
            const int col = l16 + (s << 4);
            if (col < 266) {
                const int gc = ow0 + col - 5;
                unsigned int v = 0;
                if (gc >= 0 && gc < 512)
                    v = (unsigned int)hrow[gc] |
                        ((unsigned int)hrow[gc + 81 * 512] << 16);
                *(unsigned int*)&lb[col * 40 + 2 * p] = v;
            }
        }
        __syncthreads();

        #pragma unroll
        for (int kw = 0; kw < 11; ++kw) {
            const int tap = kh * 11 + kw;
            const unsigned short* ap = w2t + tap * 1024 + l31 * 32 + lhi * 8;
            const bf16x8 a0 = *(const bf16x8*)(ap);
            const bf16x8 a1 = *(const bf16x8*)(ap + 16);
            const unsigned short* bp = &lb[((w << 6) + l31 + kw) * 40 + lhi * 8];
            const bf16x8 b00 = *(const bf16x8*)(bp);
            const bf16x8 b01 = *(const bf16x8*)(bp + 16);
            const bf16x8 b10 = *(const bf16x8*)(bp + 32 * 40);
            const bf16x8 b11 = *(const bf16x8*)(bp + 32 * 40 + 16);
            acc0 = __builtin_amdgcn_mfma_f32_32x32x16_bf16(a0, b00, acc0, 0, 0, 0);
            acc0 = __builtin_amdgcn_mfma_f32_32x32x16_bf16(a1, b01, acc0, 0, 0, 0);
            acc1 = __builtin_amdgcn_mfma_f32_32x32x16_bf16(a0, b10, acc1, 0, 0, 0);
            acc1 = __builtin_amdgcn_mfma_f32_32x32x16_bf16(a1, b11, acc1, 0, 0, 0);
        }
    }

    const int len = xlen[n];
    #pragma unroll
    for (int g = 0; g < 2; ++g) {
        const int ow = ow0 + (w << 6) + (g << 5) + l31;
        const bool valid = ow < len;
        #pragma unroll
        for (int reg = 0; reg < 16; ++reg) {
            const int oc = (reg & 3) + ((reg >> 2) << 3) + (lhi << 2);
            const float s = g2[oc] * rsqrtf(v2[oc] + 1e-5f);
            float val = ((g ? acc1[reg] : acc0[reg]) + b2[oc] - m2[oc]) * s + be2[oc];
            val = fminf(fmaxf(val, 0.f), 20.f);
            if (!valid) val = 0.f;
            out[((size_t)(n * 32 + oc) * 41 + oh2) * 512 + ow] = val;
        }
    }
}

extern "C" void kernel_launch(void* const* d_in, const int* in_sizes, int n_in,
                              void* d_out, int out_size, void* d_ws, size_t ws_size,
                              hipStream_t stream) {
    const float* x    = (const float*)d_in[0];
    const int*   xlen = (const int*)  d_in[1];
    const float* w1   = (const float*)d_in[2];
    const float* b1   = (const float*)d_in[3];
    const float* g1   = (const float*)d_in[4];
    const float* be1  = (const float*)d_in[5];
    const float* m1   = (const float*)d_in[6];
    const float* v1   = (const float*)d_in[7];
    const float* w2   = (const float*)d_in[8];
    const float* b2   = (const float*)d_in[9];
    const float* g2   = (const float*)d_in[10];
    const float* be2  = (const float*)d_in[11];
    const float* m2   = (const float*)d_in[12];
    const float* v2   = (const float*)d_in[13];
    float* out = (float*)d_out;

    // ws: h1 bf16 [21233664], w2t bf16 [236544], w1t bf16 [16896]
    unsigned short* h1  = (unsigned short*)d_ws;
    unsigned short* w2t = h1 + 21233664;
    unsigned short* w1t = w2t + 236544;

    prep_w1t<<<dim3(66),  dim3(256), 0, stream>>>(w1, w1t);
    prep_w2 <<<dim3(924), dim3(256), 0, stream>>>(w2, w2t);
    conv1_mfma<<<dim3(4, 41, 16), dim3(256), 0, stream>>>(
        x, xlen, w1t, b1, g1, be1, m1, v1, h1);
    conv2_fused<<<dim3(2, 41, 16), dim3(256), 0, stream>>>(
        h1, w2t, xlen, b2, g2, be2, m2, v2, out);
}

// Round 3
// 317.053 us; speedup vs baseline: 2.1936x; 1.2232x over previous
//
#include <hip/hip_runtime.h>

typedef __attribute__((ext_vector_type(8))) __bf16 bf16x8;
typedef __attribute__((ext_vector_type(16))) float f32x16;

__device__ __forceinline__ unsigned short f2bf(float f) {
    unsigned int u = __float_as_uint(f);
    unsigned int r = (u + 0x7FFFu + ((u >> 16) & 1u)) >> 16;
    return (unsigned short)r;
}

// async global->LDS, 16B per lane (m97 pattern)
#define GLL16(gp, lp) \
    __builtin_amdgcn_global_load_lds( \
        (const __attribute__((address_space(1))) unsigned int*)(gp), \
        (__attribute__((address_space(3))) unsigned int*)(lp), 16, 0, 0)

// ---------------------------------------------------------------------------
// prep_w1t: w1 [32oc][1][41kh][11kw] f32 -> w1t [kw][oc][kh pad 48] bf16.
// ---------------------------------------------------------------------------
__global__ __launch_bounds__(256) void prep_w1t(const float* __restrict__ w1,
                                                unsigned short* __restrict__ w1t)
{
    const int t = blockIdx.x * 256 + threadIdx.x;   // 66 blocks -> exactly 16896
    const int k    = t % 48;
    const int rest = t / 48;
    const int oc   = rest & 31;
    const int kw   = rest >> 5;
    unsigned short v = 0;
    if (k < 41) v = f2bf(w1[(oc * 41 + k) * 11 + kw]);
    w1t[t] = v;
}

// ---------------------------------------------------------------------------
// prep_w2f: w2 [32oc][32ic][21][11] f32 -> dense A-fragments for 32x32x16:
//   w2tf[kh6 0..32][kw 0..10][s 0..1][lane 0..63][8 bf16]
// element (ti,s,l,j): oc=l&31, ic=s*16+(l>>5)*8+j, kh=kh6-6 (zero if OOB).
// Zero-padded kh lets conv2 run branchless over j.
// ---------------------------------------------------------------------------
__global__ __launch_bounds__(256) void prep_w2f(const float* __restrict__ w2,
                                                unsigned short* __restrict__ w2tf)
{
    const int gid = blockIdx.x * 256 + threadIdx.x;  // 1452 blocks -> 371712 exact
    const int j  = gid & 7;
    const int l  = (gid >> 3) & 63;
    const int s  = (gid >> 9) & 1;
    const int ti = gid >> 10;        // 0..362
    const int kh6 = ti / 11;
    const int kw  = ti - kh6 * 11;
    const int kh  = kh6 - 6;
    const int oc  = l & 31;
    const int ic  = s * 16 + ((l >> 5) << 3) + j;
    unsigned short v = 0;
    if ((unsigned)kh <= 20u)
        v = f2bf(w2[((oc * 32 + ic) * 21 + kh) * 11 + kw]);
    w2tf[gid] = v;
}

// ---------------------------------------------------------------------------
// zero_halo: zero the halo cols (c<5, c>=517) of h1s for all (n, r).
// h1s layout: [n][r 0..80][c 0..527][64B = 32 ic bf16, chunk-swizzled]
// ---------------------------------------------------------------------------
__global__ __launch_bounds__(256) void zero_halo(unsigned short* __restrict__ h1s)
{
    const int id = blockIdx.x * 256 + threadIdx.x;   // 324 blocks -> 82944 exact
    const int p  = id & 3;
    const int k  = (id >> 2) & 15;
    const int nr = id >> 6;                          // 0..1295
    const int c  = k + (k >= 5 ? 512 : 0);           // 0..4, 517..527
    uint4 z = {0u, 0u, 0u, 0u};
    *(uint4*)((char*)h1s + ((size_t)nr * 528 + c) * 64 + p * 16) = z;
}

// ---------------------------------------------------------------------------
// conv1_mfma: conv1 (41x11, s(2,2), p(20,5)) + bias + bn1 + clip + mask,
// 11 kw-taps of M=32(oc) x K=48(kh zero-pad) x N=ow GEMM on mfma_32x32x16_bf16.
// Epilogue transposes through LDS and stores h1s in the conv2-native swizzled
// layout (dense 16B stores). Dead (fully masked) col-strips store zeros only.
// grid (4 ow-tiles, 41 oh-groups, 16 n), block 256.
// ---------------------------------------------------------------------------
__global__ __launch_bounds__(256) void conv1_mfma(
    const float* __restrict__ x, const int* __restrict__ xlen,
    const unsigned short* __restrict__ w1t,
    const float* __restrict__ b1, const float* __restrict__ g1,
    const float* __restrict__ be1, const float* __restrict__ m1,
    const float* __restrict__ v1,
    unsigned short* __restrict__ h1s)
{
    __shared__ uint4 lds4[2128];            // 34048 B: x-tile, then transpose buf
    char* lds = (char*)lds4;

    const int t  = threadIdx.x;
    const int bx = blockIdx.x;
    const int yi = blockIdx.y;
    const int n  = blockIdx.z;
    const int oh0 = ((yi >> 2) << 3) + (yi & 3);   // covers oh 0..80 with +4 pair
    const int len = xlen[n];

    const int l   = t & 63;
    const int w   = t >> 6;
    const int l31 = l & 31;
    const int lhi = l >> 5;

    // dead strip: all cols masked -> store zeros, skip everything
    if (bx * 128 >= len) {
        #pragma unroll
        for (int it = 0; it < 4; ++it) {
            const int idx = t + it * 256;
            const int d1 = idx >> 9, rem = idx & 511;
            const int cl = rem >> 2, p = rem & 3;
            const int oh = oh0 + 4 * d1;
            if (oh <= 80) {
                uint4 z = {0u, 0u, 0u, 0u};
                *(uint4*)((char*)h1s + (((size_t)n * 81 + oh) * 528 + 5 + (bx << 7) + cl) * 64 + p * 16) = z;
            }
        }
        return;
    }

    // ---- stage x: f32 -> bf16, transposed, swizzled ----
    const int cw   = t & 63;
    const int jrow = t >> 6;
    const int gr0  = 2 * oh0 - 20;
    const int gc0  = bx * 256 - 5;
    const float* xn = x + (size_t)n * 161 * 1024;
    #pragma unroll
    for (int cg = 0; cg < 5; ++cg) {
        const int c = cg * 64 + cw;
        if (c < 266) {
            const int gc = gc0 + c;
            const bool cok = (gc >= 0) && (gc < 1024);
            #pragma unroll
            for (int jj = 0; jj < 2; ++jj) {
                const int j = jrow + 4 * jj;       // chunk 0..6
                if (j < 7) {
                    unsigned int u[4];
                    #pragma unroll
                    for (int q = 0; q < 4; ++q) {
                        const int rA = gr0 + 8 * j + 2 * q;
                        float lo = 0.f, hi = 0.f;
                        if (cok && rA >= 0 && rA < 161)         lo = xn[(size_t)rA * 1024 + gc];
                        if (cok && rA + 1 >= 0 && rA + 1 < 161) hi = xn[(size_t)(rA + 1) * 1024 + gc];
                        u[q] = (unsigned int)f2bf(lo) | ((unsigned int)f2bf(hi) << 16);
                    }
                    uint4 val; val.x = u[0]; val.y = u[1]; val.z = u[2]; val.w = u[3];
                    *(uint4*)(lds + c * 128 + ((j ^ ((c >> 1) & 7)) << 4)) = val;
                }
            }
        }
    }
    __syncthreads();

    // ---- compute ----
    const int i = (w << 5) + l31;        // 0..127: ow within tile

    f32x16 acc0 = {}, acc1 = {};
    const char* w1tb = (const char*)w1t;
    #pragma unroll
    for (int kw = 0; kw < 11; ++kw) {
        const char* ap = w1tb + kw * 3072 + l31 * 96 + lhi * 16;
        const bf16x8 a0 = *(const bf16x8*)(ap);
        const bf16x8 a1 = *(const bf16x8*)(ap + 32);
        const bf16x8 a2 = *(const bf16x8*)(ap + 64);
        const int c = 2 * i + kw;
        const char* cb = lds + c * 128;
        const int sw = (c >> 1) & 7;
        const bf16x8 b00 = *(const bf16x8*)(cb + (((0 + lhi) ^ sw) << 4));
        const bf16x8 b01 = *(const bf16x8*)(cb + (((2 + lhi) ^ sw) << 4));
        const bf16x8 b02 = *(const bf16x8*)(cb + (((4 + lhi) ^ sw) << 4));
        const bf16x8 b10 = *(const bf16x8*)(cb + (((1 + lhi) ^ sw) << 4));
        const bf16x8 b11 = *(const bf16x8*)(cb + (((3 + lhi) ^ sw) << 4));
        const bf16x8 b12 = *(const bf16x8*)(cb + (((5 + lhi) ^ sw) << 4));
        acc0 = __builtin_amdgcn_mfma_f32_32x32x16_bf16(a0, b00, acc0, 0, 0, 0);
        acc0 = __builtin_amdgcn_mfma_f32_32x32x16_bf16(a1, b01, acc0, 0, 0, 0);
        acc0 = __builtin_amdgcn_mfma_f32_32x32x16_bf16(a2, b02, acc0, 0, 0, 0);
        acc1 = __builtin_amdgcn_mfma_f32_32x32x16_bf16(a0, b10, acc1, 0, 0, 0);
        acc1 = __builtin_amdgcn_mfma_f32_32x32x16_bf16(a1, b11, acc1, 0, 0, 0);
        acc1 = __builtin_amdgcn_mfma_f32_32x32x16_bf16(a2, b12, acc1, 0, 0, 0);
    }

    // ---- epilogue: bn1+clip+mask -> LDS transpose (swizzled) -> h1s ----
    __syncthreads();                     // x-tile reads done; reuse LDS
    const int sw1 = ((i + 5) >> 1) & 3;  // h1s col = 5 + bx*128 + i
    const int ow  = bx * 128 + i;
    const bool vmask = ow < len;
    #pragma unroll
    for (int d1 = 0; d1 < 2; ++d1) {
        const int oh = oh0 + 4 * d1;
        if (oh <= 80) {
            #pragma unroll
            for (int q = 0; q < 4; ++q) {
                float vv[4];
                #pragma unroll
                for (int rr = 0; rr < 4; ++rr) {
                    const int reg = (q << 2) + rr;
                    const int oc  = rr + (q << 3) + (lhi << 2);
                    const float s = g1[oc] * rsqrtf(v1[oc] + 1e-5f);
                    float val = ((d1 ? acc1[reg] : acc0[reg]) + b1[oc] - m1[oc]) * s + be1[oc];
                    val = fminf(fmaxf(val, 0.f), 20.f);
                    vv[rr] = vmask ? val : 0.f;
                }
                uint2 pk;
                pk.x = (unsigned int)f2bf(vv[0]) | ((unsigned int)f2bf(vv[1]) << 16);
                pk.y = (unsigned int)f2bf(vv[2]) | ((unsigned int)f2bf(vv[3]) << 16);
                *(uint2*)(lds + (d1 * 128 + i) * 64 + ((q ^ sw1) << 4) + lhi * 8) = pk;
            }
        }
    }
    __syncthreads();
    #pragma unroll
    for (int it = 0; it < 4; ++it) {
        const int idx = t + it * 256;
        const int d1 = idx >> 9, rem = idx & 511;
        const int cl = rem >> 2, p = rem & 3;
        const int oh = oh0 + 4 * d1;
        if (oh <= 80) {
            const uint4 v = *(const uint4*)(lds + (d1 * 128 + cl) * 64 + p * 16);
            *(uint4*)((char*)h1s + (((size_t)n * 81 + oh) * 528 + 5 + (bx << 7) + cl) * 64 + p * 16) = v;
        }
    }
}

// ---------------------------------------------------------------------------
// conv2_v3: conv2 (32ic, 21x11, s(2,1), p(10,5)) + bias + bn2 + clip + mask.
// Block = 4 waves x 256 cols x 4 oh2 rows. Loops the 27 h-rows of the group;
// each staged row is B-multicast to 4 oh2 accumulators (B:MFMA = 1:4).
// Staging: 5x global_load_lds dwordx4/thread/row, double-buffered, 1 barrier.
// A: dense w2tf frags (branchless via kh zero-pad). grid (2, 11, 16).
// ---------------------------------------------------------------------------
__global__ __launch_bounds__(256, 2) void conv2_v3(
    const unsigned short* __restrict__ h1s, const unsigned short* __restrict__ w2tf,
    const int* __restrict__ xlen,
    const float* __restrict__ b2, const float* __restrict__ g2,
    const float* __restrict__ be2, const float* __restrict__ m2,
    const float* __restrict__ v2, float* __restrict__ out)
{
    __shared__ char lbuf[2][17408];      // 272 cols x 64B, double-buffered

    const int t   = threadIdx.x;
    const int w   = t >> 6;
    const int l   = t & 63;
    const int l31 = l & 31;
    const int lhi = l >> 5;
    const int bx  = blockIdx.x;
    const int by  = blockIdx.y;
    const int n   = blockIdx.z;
    const int ow0 = bx << 8;
    const int len = xlen[n];

    if (ow0 >= len) {                    // fully masked col-tile: zeros only
        #pragma unroll
        for (int j = 0; j < 4; ++j) {
            const int oh2 = 4 * by + j;
            if (oh2 <= 40) {
                #pragma unroll
                for (int g = 0; g < 2; ++g) {
                    const int ow = ow0 + (w << 6) + (g << 5) + l31;
                    #pragma unroll
                    for (int reg = 0; reg < 16; ++reg) {
                        const int oc = (reg & 3) + ((reg >> 2) << 3) + (lhi << 2);
                        out[((size_t)(n * 32 + oc) * 41 + oh2) * 512 + ow] = 0.f;
                    }
                }
            }
        }
        return;
    }

    const int oh2max = (4 * by + 3 < 40) ? 4 * by + 3 : 40;
    const int rlo = (8 * by - 10 > 0) ? 8 * by - 10 : 0;
    const int rhi = (2 * oh2max + 10 < 80) ? 2 * oh2max + 10 : 80;

    f32x16 acc[4][2] = {};

    const char* h8 = (const char*)h1s;
    const size_t rowpitch = 528 * 64;
    const size_t nbase = (size_t)n * 81 * rowpitch + (size_t)ow0 * 64;

    {   // prologue: stage rlo into buf 0
        const char* s8 = h8 + nbase + (size_t)rlo * rowpitch;
        char* d8 = &lbuf[0][0];
        #pragma unroll
        for (int it = 0; it < 4; ++it)
            GLL16(s8 + t * 16 + it * 4096, d8 + t * 16 + it * 4096);
        if (t < 64) GLL16(s8 + t * 16 + 16384, d8 + t * 16 + 16384);
    }
    __syncthreads();

    int cur = 0;
    for (int r = rlo; r <= rhi; ++r) {
        if (r < rhi) {                   // prefetch next row into other buffer
            const char* s8 = h8 + nbase + (size_t)(r + 1) * rowpitch;
            char* d8 = &lbuf[cur ^ 1][0];
            #pragma unroll
            for (int it = 0; it < 4; ++it)
                GLL16(s8 + t * 16 + it * 4096, d8 + t * 16 + it * 4096);
            if (t < 64) GLL16(s8 + t * 16 + 16384, d8 + t * 16 + 16384);
        }
        const char* lb8 = &lbuf[cur][0];
        const int kh6base = r + 16 - 8 * by;          // kh6_j = kh6base - 2j
        const char* w8v = (const char*)w2tf;
        #pragma unroll
        for (int kw = 0; kw < 11; ++kw) {
            #pragma unroll
            for (int s = 0; s < 2; ++s) {
                const int chunk = 2 * s + lhi;
                const int lc0 = (w << 6) + l31 + kw;
                const bf16x8 B0 = *(const bf16x8*)(lb8 + lc0 * 64 + ((chunk ^ ((lc0 >> 1) & 3)) << 4));
                const int lc1 = lc0 + 32;
                const bf16x8 B1 = *(const bf16x8*)(lb8 + lc1 * 64 + ((chunk ^ ((lc1 >> 1) & 3)) << 4));
                #pragma unroll
                for (int j = 0; j < 4; ++j) {
                    const int kh6 = kh6base - 2 * j;
                    const bf16x8 A = *(const bf16x8*)(w8v + (((kh6 * 11 + kw) * 2 + s) << 10) + (l << 4));
                    acc[j][0] = __builtin_amdgcn_mfma_f32_32x32x16_bf16(A, B0, acc[j][0], 0, 0, 0);
                    acc[j][1] = __builtin_amdgcn_mfma_f32_32x32x16_bf16(A, B1, acc[j][1], 0, 0, 0);
                }
            }
        }
        __syncthreads();
        cur ^= 1;
    }

    // ---- epilogue: bias + bn2 + clip + mask -> out ----
    #pragma unroll
    for (int j = 0; j < 4; ++j) {
        const int oh2 = 4 * by + j;
        if (oh2 <= 40) {
            #pragma unroll
            for (int g = 0; g < 2; ++g) {
                const int ow = ow0 + (w << 6) + (g << 5) + l31;
                const bool valid = ow < len;
                #pragma unroll
                for (int reg = 0; reg < 16; ++reg) {
                    const int oc = (reg & 3) + ((reg >> 2) << 3) + (lhi << 2);
                    const float s = g2[oc] * rsqrtf(v2[oc] + 1e-5f);
                    float val = (acc[j][g][reg] + b2[oc] - m2[oc]) * s + be2[oc];
                    val = fminf(fmaxf(val, 0.f), 20.f);
                    if (!valid) val = 0.f;
                    out[((size_t)(n * 32 + oc) * 41 + oh2) * 512 + ow] = val;
                }
            }
        }
    }
}

extern "C" void kernel_launch(void* const* d_in, const int* in_sizes, int n_in,
                              void* d_out, int out_size, void* d_ws, size_t ws_size,
                              hipStream_t stream) {
    const float* x    = (const float*)d_in[0];
    const int*   xlen = (const int*)  d_in[1];
    const float* w1   = (const float*)d_in[2];
    const float* b1   = (const float*)d_in[3];
    const float* g1   = (const float*)d_in[4];
    const float* be1  = (const float*)d_in[5];
    const float* m1   = (const float*)d_in[6];
    const float* v1   = (const float*)d_in[7];
    const float* w2   = (const float*)d_in[8];
    const float* b2   = (const float*)d_in[9];
    const float* g2   = (const float*)d_in[10];
    const float* be2  = (const float*)d_in[11];
    const float* m2   = (const float*)d_in[12];
    const float* v2   = (const float*)d_in[13];
    float* out = (float*)d_out;

    // ws: h1s [16*81*528*32 shorts = 43.8MB], w2tf [371712], w1t [16896]
    unsigned short* h1s  = (unsigned short*)d_ws;
    unsigned short* w2tf = h1s + 21897216;
    unsigned short* w1t  = w2tf + 371712;

    prep_w1t<<<dim3(66),   dim3(256), 0, stream>>>(w1, w1t);
    prep_w2f<<<dim3(1452), dim3(256), 0, stream>>>(w2, w2tf);
    zero_halo<<<dim3(324), dim3(256), 0, stream>>>(h1s);
    conv1_mfma<<<dim3(4, 41, 16), dim3(256), 0, stream>>>(
        x, xlen, w1t, b1, g1, be1, m1, v1, h1s);
    conv2_v3<<<dim3(2, 11, 16), dim3(256), 0, stream>>>(
        h1s, w2tf, xlen, b2, g2, be2, m2, v2, out);
}

// Round 4
// 229.292 us; speedup vs baseline: 3.0331x; 1.3827x over previous
//
#include <hip/hip_runtime.h>

typedef __attribute__((ext_vector_type(8))) __bf16 bf16x8;
typedef __attribute__((ext_vector_type(16))) float f32x16;

__device__ __forceinline__ unsigned short f2bf(float f) {
    unsigned int u = __float_as_uint(f);
    unsigned int r = (u + 0x7FFFu + ((u >> 16) & 1u)) >> 16;
    return (unsigned short)r;
}

// async global->LDS, 16B per lane (m97 pattern)
#define GLL16(gp, lp) \
    __builtin_amdgcn_global_load_lds( \
        (const __attribute__((address_space(1))) unsigned int*)(gp), \
        (__attribute__((address_space(3))) unsigned int*)(lp), 16, 0, 0)

// ---------------------------------------------------------------------------
// prep_w1t: w1 [32oc][1][41kh][11kw] f32 -> w1t [kw][oc][kh pad 48] bf16.
// ---------------------------------------------------------------------------
__global__ __launch_bounds__(256) void prep_w1t(const float* __restrict__ w1,
                                                unsigned short* __restrict__ w1t)
{
    const int t = blockIdx.x * 256 + threadIdx.x;   // 66 blocks -> exactly 16896
    const int k    = t % 48;
    const int rest = t / 48;
    const int oc   = rest & 31;
    const int kw   = rest >> 5;
    unsigned short v = 0;
    if (k < 41) v = f2bf(w1[(oc * 41 + k) * 11 + kw]);
    w1t[t] = v;
}

// ---------------------------------------------------------------------------
// prep_w2f: w2 [32oc][32ic][21][11] f32 -> dense A-fragments for 32x32x16:
//   w2tf[khp 0..24][kw 0..10][s 0..1][lane 0..63][8 bf16],  kh = khp - 2
// (zero outside [0,20]; khp pad lets conv2's j-loop run branchless, J=2).
// element: oc = l&31, ic = s*16 + (l>>5)*8 + j.
// ---------------------------------------------------------------------------
__global__ __launch_bounds__(256) void prep_w2f(const float* __restrict__ w2,
                                                unsigned short* __restrict__ w2tf)
{
    const int gid = blockIdx.x * 256 + threadIdx.x;  // 1100 blocks -> 281600 exact
    const int j  = gid & 7;
    const int l  = (gid >> 3) & 63;
    const int s  = (gid >> 9) & 1;
    const int ti = gid >> 10;        // 0..274
    const int khp = ti / 11;
    const int kw  = ti - khp * 11;
    const int kh  = khp - 2;
    const int oc  = l & 31;
    const int ic  = s * 16 + ((l >> 5) << 3) + j;
    unsigned short v = 0;
    if ((unsigned)kh <= 20u)
        v = f2bf(w2[((oc * 32 + ic) * 21 + kh) * 11 + kw]);
    w2tf[gid] = v;
}

// ---------------------------------------------------------------------------
// zero_halo: zero halo cols (c<5, c>=517) of planar h1s for all (n,r,icq).
// h1s layout: [n][r 0..80][icq 0..3][c 0..527][16B]  (plane = 8448 B)
// ---------------------------------------------------------------------------
__global__ __launch_bounds__(256) void zero_halo(unsigned short* __restrict__ h1s)
{
    const int id  = blockIdx.x * 256 + threadIdx.x;  // 324 blocks -> 82944 exact
    const int c16 = id & 15;
    const int q   = (id >> 4) & 3;
    const int nr  = id >> 6;                         // 0..1295
    const int c   = c16 < 5 ? c16 : 512 + c16;       // 0..4, 517..527
    uint4 z = {0u, 0u, 0u, 0u};
    *(uint4*)((char*)h1s + ((size_t)(nr * 4 + q) * 528 + c) * 16) = z;
}

// ---------------------------------------------------------------------------
// conv1_mfma: conv1 (41x11, s(2,2), p(20,5)) + bias + bn1 + clip + mask,
// 11 kw-taps of M=32(oc) x K=48(kh zero-pad) x N=ow GEMM on mfma_32x32x16_bf16.
// Epilogue transposes through LDS into the planar h1s layout (dense 16B
// stores). Dead (fully masked) col-strips store zeros only.
// grid (4 ow-tiles, 41 oh-groups, 16 n), block 256.
// ---------------------------------------------------------------------------
__global__ __launch_bounds__(256) void conv1_mfma(
    const float* __restrict__ x, const int* __restrict__ xlen,
    const unsigned short* __restrict__ w1t,
    const float* __restrict__ b1, const float* __restrict__ g1,
    const float* __restrict__ be1, const float* __restrict__ m1,
    const float* __restrict__ v1,
    unsigned short* __restrict__ h1s)
{
    __shared__ uint4 lds4[2128];            // 34048 B: x-tile, then transpose buf
    char* lds = (char*)lds4;

    const int t  = threadIdx.x;
    const int bx = blockIdx.x;
    const int yi = blockIdx.y;
    const int n  = blockIdx.z;
    const int oh0 = ((yi >> 2) << 3) + (yi & 3);   // covers oh 0..80 with +4 pair
    const int len = xlen[n];

    const int l   = t & 63;
    const int w   = t >> 6;
    const int l31 = l & 31;
    const int lhi = l >> 5;

    char* h8 = (char*)h1s;
    const size_t rowpitch = 33792;          // 4 planes x 528 x 16B

    // dead strip: all cols masked -> store zeros, skip everything
    if (bx * 128 >= len) {
        #pragma unroll
        for (int it = 0; it < 4; ++it) {
            const int idx = t + it * 256;
            const int d1 = idx >> 9;
            const int q  = (idx >> 7) & 3;
            const int cl = idx & 127;
            const int oh = oh0 + 4 * d1;
            if (oh <= 80) {
                uint4 z = {0u, 0u, 0u, 0u};
                *(uint4*)(h8 + (size_t)(n * 81 + oh) * rowpitch + q * 8448
                          + (5 + (bx << 7) + cl) * 16) = z;
            }
        }
        return;
    }

    // ---- stage x: f32 -> bf16, transposed, swizzled ----
    const int cw   = t & 63;
    const int jrow = t >> 6;
    const int gr0  = 2 * oh0 - 20;
    const int gc0  = bx * 256 - 5;
    const float* xn = x + (size_t)n * 161 * 1024;
    #pragma unroll
    for (int cg = 0; cg < 5; ++cg) {
        const int c = cg * 64 + cw;
        if (c < 266) {
            const int gc = gc0 + c;
            const bool cok = (gc >= 0) && (gc < 1024);
            #pragma unroll
            for (int jj = 0; jj < 2; ++jj) {
                const int j = jrow + 4 * jj;       // chunk 0..6
                if (j < 7) {
                    unsigned int u[4];
                    #pragma unroll
                    for (int q = 0; q < 4; ++q) {
                        const int rA = gr0 + 8 * j + 2 * q;
                        float lo = 0.f, hi = 0.f;
                        if (cok && rA >= 0 && rA < 161)         lo = xn[(size_t)rA * 1024 + gc];
                        if (cok && rA + 1 >= 0 && rA + 1 < 161) hi = xn[(size_t)(rA + 1) * 1024 + gc];
                        u[q] = (unsigned int)f2bf(lo) | ((unsigned int)f2bf(hi) << 16);
                    }
                    uint4 val; val.x = u[0]; val.y = u[1]; val.z = u[2]; val.w = u[3];
                    *(uint4*)(lds + c * 128 + ((j ^ ((c >> 1) & 7)) << 4)) = val;
                }
            }
        }
    }
    __syncthreads();

    // ---- compute ----
    const int i = (w << 5) + l31;        // 0..127: ow within tile

    f32x16 acc0 = {}, acc1 = {};
    const char* w1tb = (const char*)w1t;
    #pragma unroll
    for (int kw = 0; kw < 11; ++kw) {
        const char* ap = w1tb + kw * 3072 + l31 * 96 + lhi * 16;
        const bf16x8 a0 = *(const bf16x8*)(ap);
        const bf16x8 a1 = *(const bf16x8*)(ap + 32);
        const bf16x8 a2 = *(const bf16x8*)(ap + 64);
        const int c = 2 * i + kw;
        const char* cb = lds + c * 128;
        const int sw = (c >> 1) & 7;
        const bf16x8 b00 = *(const bf16x8*)(cb + (((0 + lhi) ^ sw) << 4));
        const bf16x8 b01 = *(const bf16x8*)(cb + (((2 + lhi) ^ sw) << 4));
        const bf16x8 b02 = *(const bf16x8*)(cb + (((4 + lhi) ^ sw) << 4));
        const bf16x8 b10 = *(const bf16x8*)(cb + (((1 + lhi) ^ sw) << 4));
        const bf16x8 b11 = *(const bf16x8*)(cb + (((3 + lhi) ^ sw) << 4));
        const bf16x8 b12 = *(const bf16x8*)(cb + (((5 + lhi) ^ sw) << 4));
        acc0 = __builtin_amdgcn_mfma_f32_32x32x16_bf16(a0, b00, acc0, 0, 0, 0);
        acc0 = __builtin_amdgcn_mfma_f32_32x32x16_bf16(a1, b01, acc0, 0, 0, 0);
        acc0 = __builtin_amdgcn_mfma_f32_32x32x16_bf16(a2, b02, acc0, 0, 0, 0);
        acc1 = __builtin_amdgcn_mfma_f32_32x32x16_bf16(a0, b10, acc1, 0, 0, 0);
        acc1 = __builtin_amdgcn_mfma_f32_32x32x16_bf16(a1, b11, acc1, 0, 0, 0);
        acc1 = __builtin_amdgcn_mfma_f32_32x32x16_bf16(a2, b12, acc1, 0, 0, 0);
    }

    // ---- epilogue: bn1+clip+mask -> LDS transpose (planar) -> h1s ----
    __syncthreads();                     // x-tile reads done; reuse LDS
    const int ow  = bx * 128 + i;
    const bool vmask = ow < len;
    #pragma unroll
    for (int d1 = 0; d1 < 2; ++d1) {
        const int oh = oh0 + 4 * d1;
        if (oh <= 80) {
            #pragma unroll
            for (int q = 0; q < 4; ++q) {   // q = icq plane (oc>>3)
                float vv[4];
                #pragma unroll
                for (int rr = 0; rr < 4; ++rr) {
                    const int reg = (q << 2) + rr;
                    const int oc  = rr + (q << 3) + (lhi << 2);
                    const float s = g1[oc] * rsqrtf(v1[oc] + 1e-5f);
                    float val = ((d1 ? acc1[reg] : acc0[reg]) + b1[oc] - m1[oc]) * s + be1[oc];
                    val = fminf(fmaxf(val, 0.f), 20.f);
                    vv[rr] = vmask ? val : 0.f;
                }
                uint2 pk;
                pk.x = (unsigned int)f2bf(vv[0]) | ((unsigned int)f2bf(vv[1]) << 16);
                pk.y = (unsigned int)f2bf(vv[2]) | ((unsigned int)f2bf(vv[3]) << 16);
                // buffer layout [d1][q][i 0..127][16B]; lane writes 8B at +lhi*8
                *(uint2*)(lds + (((d1 << 2) + q) << 11) + i * 16 + lhi * 8) = pk;
            }
        }
    }
    __syncthreads();
    #pragma unroll
    for (int it = 0; it < 4; ++it) {
        const int idx = t + it * 256;    // 0..1023
        const int d1 = idx >> 9;
        const int q  = (idx >> 7) & 3;
        const int cl = idx & 127;
        const int oh = oh0 + 4 * d1;
        if (oh <= 80) {
            const uint4 v = *(const uint4*)(lds + (((d1 << 2) + q) << 11) + cl * 16);
            *(uint4*)(h8 + (size_t)(n * 81 + oh) * rowpitch + q * 8448
                      + (5 + (bx << 7) + cl) * 16) = v;
        }
    }
}

// ---------------------------------------------------------------------------
// conv2_v4: conv2 (32ic, 21x11, s(2,1), p(10,5)) + bias + bn2 + clip + mask.
// Block = 4 waves x 256 cols x 2 oh2 rows (J=2).  Grid 672 blocks, decoded
// from an XCD-chunked id so each XCD owns exactly 2 n-slabs (L2-resident).
// Per staged row: B multicast to 2 oh2 accumulators; planar LDS ->
// contiguous-512B B-reads (conflict-free); A-frags streamed from L2 (w2tf).
// ---------------------------------------------------------------------------
__global__ __launch_bounds__(256, 2) void conv2_v4(
    const unsigned short* __restrict__ h1s, const unsigned short* __restrict__ w2tf,
    const int* __restrict__ xlen,
    const float* __restrict__ b2, const float* __restrict__ g2,
    const float* __restrict__ be2, const float* __restrict__ m2,
    const float* __restrict__ v2, float* __restrict__ out)
{
    __shared__ char lbuf[2][20480];      // 2 x (4 planes x 5120B pad)

    const int t   = threadIdx.x;
    const int w   = t >> 6;
    const int l   = t & 63;
    const int l31 = l & 31;
    const int lhi = l >> 5;

    // XCD-chunked bijective swizzle: 672 = 8 * 84; chunk c owns n = {2c, 2c+1}
    const int bid = blockIdx.x;
    const int lb  = (bid & 7) * 84 + (bid >> 3);
    const int bx  = lb & 1;
    const int rest = lb >> 1;            // 0..335
    const int by  = rest % 21;           // oh2 pair {2by, 2by+1}
    const int n   = rest / 21;

    const int ow0 = bx << 8;
    const int len = xlen[n];

    if (ow0 >= len) {                    // fully masked col-tile: zeros only
        #pragma unroll
        for (int j = 0; j < 2; ++j) {
            const int oh2 = 2 * by + j;
            if (oh2 <= 40) {
                #pragma unroll
                for (int g = 0; g < 2; ++g) {
                    const int ow = ow0 + (w << 6) + (g << 5) + l31;
                    #pragma unroll
                    for (int reg = 0; reg < 16; ++reg) {
                        const int oc = (reg & 3) + ((reg >> 2) << 3) + (lhi << 2);
                        out[((size_t)(n * 32 + oc) * 41 + oh2) * 512 + ow] = 0.f;
                    }
                }
            }
        }
        return;
    }

    const int rlo = (4 * by - 10 > 0) ? 4 * by - 10 : 0;
    const int rhi = (4 * by + 12 < 80) ? 4 * by + 12 : 80;

    f32x16 acc[2][2] = {};

    const char* h8 = (const char*)h1s;
    const size_t rowpitch = 33792;
    const char* nb = h8 + (size_t)(n * 81) * rowpitch + (size_t)(ow0 << 4);

    #define STAGE(r, buf) do { \
        const char* g_ = nb + (size_t)(r) * rowpitch; \
        char* d_ = &lbuf[buf][0]; \
        _Pragma("unroll") \
        for (int pl_ = 0; pl_ < 4; ++pl_) \
            GLL16(g_ + pl_ * 8448 + t * 16, d_ + pl_ * 5120 + t * 16); \
        GLL16(g_ + w * 8448 + 4096 + (t & 63) * 16, \
              d_ + w * 5120 + 4096 + (t & 63) * 16); \
    } while (0)

    STAGE(rlo, 0);
    __syncthreads();

    int cur = 0;
    for (int r = rlo; r <= rhi; ++r) {
        if (r < rhi) STAGE(r + 1, cur ^ 1);
        const char* lb8 = &lbuf[cur][0];
        const int khb = r - 4 * by + 10;           // 0..22
        const char* w8v = (const char*)w2tf;
        #pragma unroll
        for (int kw = 0; kw < 11; ++kw) {
            const int cbase = (w << 6) + kw + l31;
            #pragma unroll
            for (int s = 0; s < 2; ++s) {
                const char* bp = lb8 + (2 * s + lhi) * 5120 + cbase * 16;
                const bf16x8 B0 = *(const bf16x8*)(bp);
                const bf16x8 B1 = *(const bf16x8*)(bp + 512);
                #pragma unroll
                for (int j = 0; j < 2; ++j) {
                    const int khp = khb + 2 - 2 * j;   // 0..24
                    const bf16x8 A = *(const bf16x8*)(w8v
                        + (size_t)(((khp * 11 + kw) * 2 + s) << 10) + (l << 4));
                    acc[j][0] = __builtin_amdgcn_mfma_f32_32x32x16_bf16(A, B0, acc[j][0], 0, 0, 0);
                    acc[j][1] = __builtin_amdgcn_mfma_f32_32x32x16_bf16(A, B1, acc[j][1], 0, 0, 0);
                }
            }
        }
        __syncthreads();
        cur ^= 1;
    }

    // ---- epilogue: bias + bn2 + clip + mask -> out ----
    #pragma unroll
    for (int j = 0; j < 2; ++j) {
        const int oh2 = 2 * by + j;
        if (oh2 <= 40) {
            #pragma unroll
            for (int g = 0; g < 2; ++g) {
                const int ow = ow0 + (w << 6) + (g << 5) + l31;
                const bool valid = ow < len;
                #pragma unroll
                for (int reg = 0; reg < 16; ++reg) {
                    const int oc = (reg & 3) + ((reg >> 2) << 3) + (lhi << 2);
                    const float s = g2[oc] * rsqrtf(v2[oc] + 1e-5f);
                    float val = (acc[j][g][reg] + b2[oc] - m2[oc]) * s + be2[oc];
                    val = fminf(fmaxf(val, 0.f), 20.f);
                    if (!valid) val = 0.f;
                    out[((size_t)(n * 32 + oc) * 41 + oh2) * 512 + ow] = val;
                }
            }
        }
    }
}

extern "C" void kernel_launch(void* const* d_in, const int* in_sizes, int n_in,
                              void* d_out, int out_size, void* d_ws, size_t ws_size,
                              hipStream_t stream) {
    const float* x    = (const float*)d_in[0];
    const int*   xlen = (const int*)  d_in[1];
    const float* w1   = (const float*)d_in[2];
    const float* b1   = (const float*)d_in[3];
    const float* g1   = (const float*)d_in[4];
    const float* be1  = (const float*)d_in[5];
    const float* m1   = (const float*)d_in[6];
    const float* v1   = (const float*)d_in[7];
    const float* w2   = (const float*)d_in[8];
    const float* b2   = (const float*)d_in[9];
    const float* g2   = (const float*)d_in[10];
    const float* be2  = (const float*)d_in[11];
    const float* m2   = (const float*)d_in[12];
    const float* v2   = (const float*)d_in[13];
    float* out = (float*)d_out;

    // ws: h1s planar [16*81*4*528*8 shorts = 43.8MB], w2tf [281600], w1t [16896]
    unsigned short* h1s  = (unsigned short*)d_ws;
    unsigned short* w2tf = h1s + 21897216;
    unsigned short* w1t  = w2tf + 281600;

    prep_w1t<<<dim3(66),   dim3(256), 0, stream>>>(w1, w1t);
    prep_w2f<<<dim3(1100), dim3(256), 0, stream>>>(w2, w2tf);
    zero_halo<<<dim3(324), dim3(256), 0, stream>>>(h1s);
    conv1_mfma<<<dim3(4, 41, 16), dim3(256), 0, stream>>>(
        x, xlen, w1t, b1, g1, be1, m1, v1, h1s);
    conv2_v4<<<dim3(672), dim3(256), 0, stream>>>(
        h1s, w2tf, xlen, b2, g2, be2, m2, v2, out);
}

// Round 5
// 220.391 us; speedup vs baseline: 3.1556x; 1.0404x over previous
//
#include <hip/hip_runtime.h>

typedef __attribute__((ext_vector_type(8))) __bf16 bf16x8;
typedef __attribute__((ext_vector_type(16))) float f32x16;

__device__ __forceinline__ unsigned short f2bf(float f) {
    unsigned int u = __float_as_uint(f);
    unsigned int r = (u + 0x7FFFu + ((u >> 16) & 1u)) >> 16;
    return (unsigned short)r;
}

// async global->LDS, 16B per lane (m97 pattern)
#define GLL16(gp, lp) \
    __builtin_amdgcn_global_load_lds( \
        (const __attribute__((address_space(1))) unsigned int*)(gp), \
        (__attribute__((address_space(3))) unsigned int*)(lp), 16, 0, 0)

// ---------------------------------------------------------------------------
// prep_w1t: w1 [32oc][1][41kh][11kw] f32 -> w1t [kw][oc][kh pad 48] bf16.
// ---------------------------------------------------------------------------
__global__ __launch_bounds__(256) void prep_w1t(const float* __restrict__ w1,
                                                unsigned short* __restrict__ w1t)
{
    const int t = blockIdx.x * 256 + threadIdx.x;   // 66 blocks -> exactly 16896
    const int k    = t % 48;
    const int rest = t / 48;
    const int oc   = rest & 31;
    const int kw   = rest >> 5;
    unsigned short v = 0;
    if (k < 41) v = f2bf(w1[(oc * 41 + k) * 11 + kw]);
    w1t[t] = v;
}

// ---------------------------------------------------------------------------
// prep_w2f: w2 [32oc][32ic][21][11] f32 -> dense A-fragments for 32x32x16:
//   w2tf[khp 0..24][kw 0..10][s 0..1][lane 0..63][8 bf16],  kh = khp - 2
// (zero outside [0,20]).  element: oc = l&31, ic = s*16 + (l>>5)*8 + j.
// ---------------------------------------------------------------------------
__global__ __launch_bounds__(256) void prep_w2f(const float* __restrict__ w2,
                                                unsigned short* __restrict__ w2tf)
{
    const int gid = blockIdx.x * 256 + threadIdx.x;  // 1100 blocks -> 281600 exact
    const int j  = gid & 7;
    const int l  = (gid >> 3) & 63;
    const int s  = (gid >> 9) & 1;
    const int ti = gid >> 10;        // 0..274
    const int khp = ti / 11;
    const int kw  = ti - khp * 11;
    const int kh  = khp - 2;
    const int oc  = l & 31;
    const int ic  = s * 16 + ((l >> 5) << 3) + j;
    unsigned short v = 0;
    if ((unsigned)kh <= 20u)
        v = f2bf(w2[((oc * 32 + ic) * 21 + kh) * 11 + kw]);
    w2tf[gid] = v;
}

// ---------------------------------------------------------------------------
// zero_halo: zero halo cols (c<5, c>=517) of planar h1s for all (n,r,icq).
// h1s layout: [n][r 0..80][icq 0..3][c 0..527][16B]  (plane = 8448 B)
// ---------------------------------------------------------------------------
__global__ __launch_bounds__(256) void zero_halo(unsigned short* __restrict__ h1s)
{
    const int id  = blockIdx.x * 256 + threadIdx.x;  // 324 blocks -> 82944 exact
    const int c16 = id & 15;
    const int q   = (id >> 4) & 3;
    const int nr  = id >> 6;                         // 0..1295
    const int c   = c16 < 5 ? c16 : 512 + c16;       // 0..4, 517..527
    uint4 z = {0u, 0u, 0u, 0u};
    *(uint4*)((char*)h1s + ((size_t)(nr * 4 + q) * 528 + c) * 16) = z;
}

// ---------------------------------------------------------------------------
// conv1_mfma: conv1 (41x11, s(2,2), p(20,5)) + bias + bn1 + clip + mask,
// 11 kw-taps of M=32(oc) x K=48(kh zero-pad) x N=ow GEMM on mfma_32x32x16_bf16.
// Epilogue transposes through LDS into the planar h1s layout.
// grid (4 ow-tiles, 41 oh-groups, 16 n), block 256.
// ---------------------------------------------------------------------------
__global__ __launch_bounds__(256) void conv1_mfma(
    const float* __restrict__ x, const int* __restrict__ xlen,
    const unsigned short* __restrict__ w1t,
    const float* __restrict__ b1, const float* __restrict__ g1,
    const float* __restrict__ be1, const float* __restrict__ m1,
    const float* __restrict__ v1,
    unsigned short* __restrict__ h1s)
{
    __shared__ uint4 lds4[2128];            // 34048 B: x-tile, then transpose buf
    char* lds = (char*)lds4;

    const int t  = threadIdx.x;
    const int bx = blockIdx.x;
    const int yi = blockIdx.y;
    const int n  = blockIdx.z;
    const int oh0 = ((yi >> 2) << 3) + (yi & 3);   // covers oh 0..80 with +4 pair
    const int len = xlen[n];

    const int l   = t & 63;
    const int w   = t >> 6;
    const int l31 = l & 31;
    const int lhi = l >> 5;

    char* h8 = (char*)h1s;
    const size_t rowpitch = 33792;          // 4 planes x 528 x 16B

    // dead strip: all cols masked -> store zeros, skip everything
    if (bx * 128 >= len) {
        #pragma unroll
        for (int it = 0; it < 4; ++it) {
            const int idx = t + it * 256;
            const int d1 = idx >> 9;
            const int q  = (idx >> 7) & 3;
            const int cl = idx & 127;
            const int oh = oh0 + 4 * d1;
            if (oh <= 80) {
                uint4 z = {0u, 0u, 0u, 0u};
                *(uint4*)(h8 + (size_t)(n * 81 + oh) * rowpitch + q * 8448
                          + (5 + (bx << 7) + cl) * 16) = z;
            }
        }
        return;
    }

    // ---- stage x: f32 -> bf16, transposed, swizzled ----
    const int cw   = t & 63;
    const int jrow = t >> 6;
    const int gr0  = 2 * oh0 - 20;
    const int gc0  = bx * 256 - 5;
    const float* xn = x + (size_t)n * 161 * 1024;
    #pragma unroll
    for (int cg = 0; cg < 5; ++cg) {
        const int c = cg * 64 + cw;
        if (c < 266) {
            const int gc = gc0 + c;
            const bool cok = (gc >= 0) && (gc < 1024);
            #pragma unroll
            for (int jj = 0; jj < 2; ++jj) {
                const int j = jrow + 4 * jj;       // chunk 0..6
                if (j < 7) {
                    unsigned int u[4];
                    #pragma unroll
                    for (int q = 0; q < 4; ++q) {
                        const int rA = gr0 + 8 * j + 2 * q;
                        float lo = 0.f, hi = 0.f;
                        if (cok && rA >= 0 && rA < 161)         lo = xn[(size_t)rA * 1024 + gc];
                        if (cok && rA + 1 >= 0 && rA + 1 < 161) hi = xn[(size_t)(rA + 1) * 1024 + gc];
                        u[q] = (unsigned int)f2bf(lo) | ((unsigned int)f2bf(hi) << 16);
                    }
                    uint4 val; val.x = u[0]; val.y = u[1]; val.z = u[2]; val.w = u[3];
                    *(uint4*)(lds + c * 128 + ((j ^ ((c >> 1) & 7)) << 4)) = val;
                }
            }
        }
    }
    __syncthreads();

    // ---- compute ----
    const int i = (w << 5) + l31;        // 0..127: ow within tile

    f32x16 acc0 = {}, acc1 = {};
    const char* w1tb = (const char*)w1t;
    #pragma unroll
    for (int kw = 0; kw < 11; ++kw) {
        const char* ap = w1tb + kw * 3072 + l31 * 96 + lhi * 16;
        const bf16x8 a0 = *(const bf16x8*)(ap);
        const bf16x8 a1 = *(const bf16x8*)(ap + 32);
        const bf16x8 a2 = *(const bf16x8*)(ap + 64);
        const int c = 2 * i + kw;
        const char* cb = lds + c * 128;
        const int sw = (c >> 1) & 7;
        const bf16x8 b00 = *(const bf16x8*)(cb + (((0 + lhi) ^ sw) << 4));
        const bf16x8 b01 = *(const bf16x8*)(cb + (((2 + lhi) ^ sw) << 4));
        const bf16x8 b02 = *(const bf16x8*)(cb + (((4 + lhi) ^ sw) << 4));
        const bf16x8 b10 = *(const bf16x8*)(cb + (((1 + lhi) ^ sw) << 4));
        const bf16x8 b11 = *(const bf16x8*)(cb + (((3 + lhi) ^ sw) << 4));
        const bf16x8 b12 = *(const bf16x8*)(cb + (((5 + lhi) ^ sw) << 4));
        acc0 = __builtin_amdgcn_mfma_f32_32x32x16_bf16(a0, b00, acc0, 0, 0, 0);
        acc0 = __builtin_amdgcn_mfma_f32_32x32x16_bf16(a1, b01, acc0, 0, 0, 0);
        acc0 = __builtin_amdgcn_mfma_f32_32x32x16_bf16(a2, b02, acc0, 0, 0, 0);
        acc1 = __builtin_amdgcn_mfma_f32_32x32x16_bf16(a0, b10, acc1, 0, 0, 0);
        acc1 = __builtin_amdgcn_mfma_f32_32x32x16_bf16(a1, b11, acc1, 0, 0, 0);
        acc1 = __builtin_amdgcn_mfma_f32_32x32x16_bf16(a2, b12, acc1, 0, 0, 0);
    }

    // ---- epilogue: bn1+clip+mask -> LDS transpose (planar) -> h1s ----
    __syncthreads();                     // x-tile reads done; reuse LDS
    const int ow  = bx * 128 + i;
    const bool vmask = ow < len;
    #pragma unroll
    for (int d1 = 0; d1 < 2; ++d1) {
        const int oh = oh0 + 4 * d1;
        if (oh <= 80) {
            #pragma unroll
            for (int q = 0; q < 4; ++q) {   // q = icq plane (oc>>3)
                float vv[4];
                #pragma unroll
                for (int rr = 0; rr < 4; ++rr) {
                    const int reg = (q << 2) + rr;
                    const int oc  = rr + (q << 3) + (lhi << 2);
                    const float s = g1[oc] * rsqrtf(v1[oc] + 1e-5f);
                    float val = ((d1 ? acc1[reg] : acc0[reg]) + b1[oc] - m1[oc]) * s + be1[oc];
                    val = fminf(fmaxf(val, 0.f), 20.f);
                    vv[rr] = vmask ? val : 0.f;
                }
                uint2 pk;
                pk.x = (unsigned int)f2bf(vv[0]) | ((unsigned int)f2bf(vv[1]) << 16);
                pk.y = (unsigned int)f2bf(vv[2]) | ((unsigned int)f2bf(vv[3]) << 16);
                *(uint2*)(lds + (((d1 << 2) + q) << 11) + i * 16 + lhi * 8) = pk;
            }
        }
    }
    __syncthreads();
    #pragma unroll
    for (int it = 0; it < 4; ++it) {
        const int idx = t + it * 256;    // 0..1023
        const int d1 = idx >> 9;
        const int q  = (idx >> 7) & 3;
        const int cl = idx & 127;
        const int oh = oh0 + 4 * d1;
        if (oh <= 80) {
            const uint4 v = *(const uint4*)(lds + (((d1 << 2) + q) << 11) + cl * 16);
            *(uint4*)(h8 + (size_t)(n * 81 + oh) * rowpitch + q * 8448
                      + (5 + (bx << 7) + cl) * 16) = v;
        }
    }
}

// ---------------------------------------------------------------------------
// conv2_v5: conv2 (32ic, 21x11, s(2,1), p(10,5)) + bias + bn2 + clip + mask.
// Block = 4 waves = (col-half cg x K-half s), tile = 128 cols x 2 oh2 (J=2).
// Per wave per kw: 2 A-loads (j), 2 B-loads (f), 4 MFMA  (A=B=0.5 load/MFMA).
// s-partial accs summed via 32KB LDS reduction after the row loop.
// grid 1344 (XCD-chunked: each XCD owns 2 n-slabs), LDS 32KB -> 5 blocks/CU.
// ---------------------------------------------------------------------------
__global__ __launch_bounds__(256, 2) void conv2_v5(
    const unsigned short* __restrict__ h1s, const unsigned short* __restrict__ w2tf,
    const int* __restrict__ xlen,
    const float* __restrict__ b2, const float* __restrict__ g2,
    const float* __restrict__ be2, const float* __restrict__ m2,
    const float* __restrict__ v2, float* __restrict__ out)
{
    __shared__ char lbuf[32768];         // 2 stage bufs @9216B; 32KB reduction

    const int t   = threadIdx.x;
    const int w   = t >> 6;
    const int l   = t & 63;
    const int l31 = l & 31;
    const int lhi = l >> 5;
    const int cg  = w >> 1;              // col-half (64 cols)
    const int s   = w & 1;               // K-half (ic 16s..16s+15)

    // XCD-chunked bijective swizzle: 1344 = 8 * 168; each XCD owns 2 n
    const int bid  = blockIdx.x;
    const int lb   = (bid & 7) * 168 + (bid >> 3);
    const int n    = lb / 84;
    const int r2   = lb - n * 84;
    const int by   = r2 >> 2;            // 0..20: oh2 pair {2by, 2by+1}
    const int bx   = r2 & 3;

    const int ow0 = bx << 7;
    const int len = xlen[n];

    if (ow0 >= len) {                    // fully masked col-tile: zeros only
        const int j   = w >> 1;
        const int cgz = w & 1;
        const int oh2 = 2 * by + j;
        if (oh2 <= 40) {
            #pragma unroll
            for (int g = 0; g < 2; ++g) {
                const int ow = ow0 + (cgz << 6) + (g << 5) + l31;
                #pragma unroll
                for (int reg = 0; reg < 16; ++reg) {
                    const int oc = (reg & 3) + ((reg >> 2) << 3) + (lhi << 2);
                    out[((size_t)(n * 32 + oc) * 41 + oh2) * 512 + ow] = 0.f;
                }
            }
        }
        return;
    }

    const int rlo = (4 * by - 10 > 0) ? 4 * by - 10 : 0;
    const int rhi = (4 * by + 12 < 80) ? 4 * by + 12 : 80;

    f32x16 acc[2][2] = {};               // [j][f]

    const char* h8 = (const char*)h1s;
    const size_t rowpitch = 33792;
    const char* nb = h8 + (size_t)(n * 81) * rowpitch + (size_t)(ow0 << 4);

    // stage: 4 planes x 144 cols x 16B; wave w stages plane w (linear dest)
    #define STAGE(r, buf) do { \
        const char* g_ = nb + (size_t)(r) * rowpitch + w * 8448; \
        char* d_ = lbuf + (buf) * 9216 + w * 2304; \
        GLL16(g_ + l * 16,        d_ + l * 16); \
        GLL16(g_ + 1024 + l * 16, d_ + 1024 + l * 16); \
        if (l < 16) GLL16(g_ + 2048 + l * 16, d_ + 2048 + l * 16); \
    } while (0)

    STAGE(rlo, 0);
    __syncthreads();

    const char* w8v = (const char*)w2tf;
    int cur = 0;
    for (int r = rlo; r <= rhi; ++r) {
        if (r < rhi) STAGE(r + 1, cur ^ 1);
        const char* lb8 = lbuf + cur * 9216;
        const int khb = r - 4 * by + 10;           // 0..22
        #pragma unroll
        for (int kw = 0; kw < 11; ++kw) {
            const char* bp = lb8 + (2 * s + lhi) * 2304 + ((cg << 6) + l31 + kw) * 16;
            const bf16x8 B0 = *(const bf16x8*)(bp);
            const bf16x8 B1 = *(const bf16x8*)(bp + 512);
            #pragma unroll
            for (int j = 0; j < 2; ++j) {
                const int khp = khb + 2 - 2 * j;   // 0..24
                const bf16x8 A = *(const bf16x8*)(w8v
                    + (size_t)(((khp * 11 + kw) * 2 + s) << 10) + (l << 4));
                acc[j][0] = __builtin_amdgcn_mfma_f32_32x32x16_bf16(A, B0, acc[j][0], 0, 0, 0);
                acc[j][1] = __builtin_amdgcn_mfma_f32_32x32x16_bf16(A, B1, acc[j][1], 0, 0, 0);
            }
        }
        __syncthreads();
        cur ^= 1;
    }
    #undef STAGE

    // ---- cross-wave s-reduction via LDS ----
    if (s == 1) {
        #pragma unroll
        for (int j = 0; j < 2; ++j) {
            #pragma unroll
            for (int f = 0; f < 2; ++f) {
                char* dst = lbuf + ((((cg << 1) + j) << 1) + f) * 4096 + l * 16;
                #pragma unroll
                for (int q = 0; q < 4; ++q) {
                    float4 v;
                    v.x = acc[j][f][q * 4 + 0]; v.y = acc[j][f][q * 4 + 1];
                    v.z = acc[j][f][q * 4 + 2]; v.w = acc[j][f][q * 4 + 3];
                    *(float4*)(dst + q * 1024) = v;
                }
            }
        }
    }
    __syncthreads();
    if (s == 1) return;

    // ---- epilogue (s==0 waves): add partner acc, bn2 + clip + mask ----
    #pragma unroll
    for (int j = 0; j < 2; ++j) {
        const int oh2 = 2 * by + j;
        if (oh2 <= 40) {
            #pragma unroll
            for (int f = 0; f < 2; ++f) {
                const char* src = lbuf + ((((cg << 1) + j) << 1) + f) * 4096 + l * 16;
                float pr[16];
                #pragma unroll
                for (int q = 0; q < 4; ++q) {
                    const float4 v = *(const float4*)(src + q * 1024);
                    pr[q * 4 + 0] = v.x; pr[q * 4 + 1] = v.y;
                    pr[q * 4 + 2] = v.z; pr[q * 4 + 3] = v.w;
                }
                const int ow = ow0 + (cg << 6) + (f << 5) + l31;
                const bool valid = ow < len;
                #pragma unroll
                for (int reg = 0; reg < 16; ++reg) {
                    const int oc = (reg & 3) + ((reg >> 2) << 3) + (lhi << 2);
                    const float sc = g2[oc] * rsqrtf(v2[oc] + 1e-5f);
                    float val = (acc[j][f][reg] + pr[reg] + b2[oc] - m2[oc]) * sc + be2[oc];
                    val = fminf(fmaxf(val, 0.f), 20.f);
                    if (!valid) val = 0.f;
                    out[((size_t)(n * 32 + oc) * 41 + oh2) * 512 + ow] = val;
                }
            }
        }
    }
}

extern "C" void kernel_launch(void* const* d_in, const int* in_sizes, int n_in,
                              void* d_out, int out_size, void* d_ws, size_t ws_size,
                              hipStream_t stream) {
    const float* x    = (const float*)d_in[0];
    const int*   xlen = (const int*)  d_in[1];
    const float* w1   = (const float*)d_in[2];
    const float* b1   = (const float*)d_in[3];
    const float* g1   = (const float*)d_in[4];
    const float* be1  = (const float*)d_in[5];
    const float* m1   = (const float*)d_in[6];
    const float* v1   = (const float*)d_in[7];
    const float* w2   = (const float*)d_in[8];
    const float* b2   = (const float*)d_in[9];
    const float* g2   = (const float*)d_in[10];
    const float* be2  = (const float*)d_in[11];
    const float* m2   = (const float*)d_in[12];
    const float* v2   = (const float*)d_in[13];
    float* out = (float*)d_out;

    // ws: h1s planar [16*81*4*528*8 shorts = 43.8MB], w2tf [281600], w1t [16896]
    unsigned short* h1s  = (unsigned short*)d_ws;
    unsigned short* w2tf = h1s + 21897216;
    unsigned short* w1t  = w2tf + 281600;

    prep_w1t<<<dim3(66),   dim3(256), 0, stream>>>(w1, w1t);
    prep_w2f<<<dim3(1100), dim3(256), 0, stream>>>(w2, w2tf);
    zero_halo<<<dim3(324), dim3(256), 0, stream>>>(h1s);
    conv1_mfma<<<dim3(4, 41, 16), dim3(256), 0, stream>>>(
        x, xlen, w1t, b1, g1, be1, m1, v1, h1s);
    conv2_v5<<<dim3(1344), dim3(256), 0, stream>>>(
        h1s, w2tf, xlen, b2, g2, be2, m2, v2, out);
}